// Round 14
// baseline (319.020 us; speedup 1.0000x reference)
//
#include <hip/hip_runtime.h>

#define B_     256
#define L_     128
#define D_     6
#define F_     200
#define FA_    39
#define FB_    10
#define PAD_   127       // L-1 padding atom index
#define LMASK  127
#define NT     256
#define KC8    (F_/8)    // 25 short8 chunks per bf16 row
#define NTILE  16
#define NQ     (NTILE * D_)   // 96 pairs
#define NF     (B_ * L_ * F_) // 6,553,600 floats
#define MSZ    (F_ * F_)      // 40,000 floats per matrix
#define NNODES (B_ * L_)      // 32768
#define KP     224            // K padded to 7*32 (MFMA reads k < 224)
#define KPP    232            // LDS row stride: 464B -> bank step 20 (conflict-free)
#define KSTEPS 7
#define NTL    13             // N tiles of 16 (200 -> 208)
#define FRAG_TOTAL (14 * NTL * KSTEPS * 64)
#define PN2    16
#define NPREP  (NNODES / PN2)                     // 2048 prep blocks
#define NBF    ((FRAG_TOTAL + NT - 1) / NT)       // 319 frag blocks

typedef __attribute__((ext_vector_type(8))) short sh8;
typedef __attribute__((ext_vector_type(4))) float f32x4;

__device__ __forceinline__ float lrelu(float x) { return x >= 0.0f ? x : 0.01f * x; }
__device__ __forceinline__ float sigm(float x)  { return 1.0f / (1.0f + __expf(-x)); }
__device__ __forceinline__ float fast_tanh(float x) {   // 1 - 2/(e^2x+1), sat-correct
    const float e = __expf(2.0f * x);
    return 1.0f - 2.0f / (e + 1.0f);
}
__device__ __forceinline__ unsigned short f2b(float x) {   // fp32 -> bf16 RNE
    unsigned int u = __float_as_uint(x);
    unsigned int r = (u + 0x7FFFu + ((u >> 16) & 1u)) >> 16;
    return (unsigned short)r;
}
__device__ __forceinline__ float b2f(unsigned short u) {
    return __uint_as_float(((unsigned int)u) << 16);
}
// A-fragment from LDS bf16 [NTILE][KPP]: A[m=lane&15][k=ks*32+quad*8+j]
#define AFRAG(arr, ks) (*(const sh8*)&arr[lane & 15][(ks) * 32 + ((lane >> 4) << 3)])
__device__ __forceinline__ sh8 bfrag(const unsigned short* __restrict__ WFr,
                                     int mat, int t, int ks, int lane) {
    return *(const sh8*)(WFr + ((((size_t)mat * NTL + t) * KSTEPS + ks) * 64 + lane) * 8);
}

// ========== fused: prep (blocks [0,NPREP)) + build_frags (blocks [NPREP,..)) ==========
__global__ __launch_bounds__(NT)
void prep_frags_kernel(const float* __restrict__ atom_list, const float* __restrict__ bond_list,
                       const float* __restrict__ atom_W, const float* __restrict__ atom_b,
                       const float* __restrict__ nbr_W,
                       const float* __restrict__ attend_W,
                       const float* __restrict__ gru_Wih,
                       const float* __restrict__ gru_Whh,
                       unsigned short* __restrict__ cur0b,
                       unsigned short* __restrict__ PA, unsigned short* __restrict__ PB,
                       unsigned short* __restrict__ WF)
{
    __shared__ float wsh[F_ * (FA_ + FB_)];   // 9800 floats = 39.2 KB
    const int tid = threadIdx.x;

    if (blockIdx.x >= NPREP) {
        // ---- build_frags part: bf16 B-fragments, 14 F×F matrices, zero-padded ----
        const int i = (blockIdx.x - NPREP) * NT + tid;
        if (i >= FRAG_TOTAL) return;
        const int lane = i & 63;
        int rest = i >> 6;
        const int ks = rest % KSTEPS; rest /= KSTEPS;
        const int t  = rest % NTL;
        const int m  = rest / NTL;
        const int n  = t * 16 + (lane & 15);
        const int k0 = ks * 32 + ((lane >> 4) << 3);
        const int r = m / 7, tt = m - r * 7;
        const float* src;
        if (tt == 0)      src = attend_W + (size_t)r * MSZ;
        else if (tt <= 3) src = gru_Wih + ((size_t)r * 3 + (tt - 1)) * MSZ;
        else              src = gru_Whh + ((size_t)r * 3 + (tt - 4)) * MSZ;
        unsigned short o[8];
        #pragma unroll
        for (int j = 0; j < 8; ++j) {
            const int k = k0 + j;
            const float v = (n < F_ && k < F_) ? src[(size_t)n * F_ + k] : 0.0f;
            o[j] = f2b(v);
        }
        uint4 w;
        w.x = (unsigned int)o[0] | ((unsigned int)o[1] << 16);
        w.y = (unsigned int)o[2] | ((unsigned int)o[3] << 16);
        w.z = (unsigned int)o[4] | ((unsigned int)o[5] << 16);
        w.w = (unsigned int)o[6] | ((unsigned int)o[7] << 16);
        ((uint4*)WF)[i] = w;
        return;
    }

    // ---- prep part: weight-stationary; lane owns column f, weights in regs ----
    const int node0 = blockIdx.x * PN2;
    const int f     = tid;
    const bool valid = (f < F_);
    const int fc    = valid ? f : 0;

    float wa[FA_];
    float wn[FA_ + FB_];

    for (int i = tid; i < F_ * FA_; i += NT) wsh[i] = atom_W[i];
    __syncthreads();
    #pragma unroll
    for (int k = 0; k < FA_; ++k) wa[k] = wsh[fc * FA_ + k];
    __syncthreads();
    for (int i = tid; i < F_ * (FA_ + FB_); i += NT) wsh[i] = nbr_W[i];
    __syncthreads();
    #pragma unroll
    for (int k = 0; k < FA_ + FB_; ++k) wn[k] = wsh[fc * (FA_ + FB_) + k];
    __syncthreads();   // wn copies done -> wsh is free

    // stage the node input rows into wsh (contiguous -> fully coalesced)
    {
        const float* asrc = atom_list + (size_t)node0 * FA_;
        for (int i = tid; i < PN2 * FA_; i += NT) wsh[i] = asrc[i];
        const float* bsrc = bond_list + (size_t)node0 * FB_;
        for (int i = tid; i < PN2 * FB_; i += NT) wsh[PN2 * FA_ + i] = bsrc[i];
    }
    __syncthreads();

    const float ab = atom_b[fc];

    for (int n = 0; n < PN2; ++n) {
        const float* __restrict__ ar = &wsh[n * FA_];
        const float* __restrict__ br = &wsh[PN2 * FA_ + n * FB_];
        float accA = ab, accPA = 0.0f, accPB = 0.0f;
        #pragma unroll
        for (int k = 0; k < FA_; ++k) {
            const float a = ar[k];          // LDS broadcast (same addr all lanes)
            accA  += a * wa[k];
            accPA += a * wn[k];
        }
        #pragma unroll
        for (int k = 0; k < FB_; ++k) accPB += br[k] * wn[FA_ + k];
        if (valid) {
            const size_t o = (size_t)(node0 + n) * F_ + f;
            cur0b[o] = f2b(lrelu(accA));
            PA[o]    = f2b(accPA);
            PB[o]    = f2b(accPB);
        }
    }
}

// ===================== round kernel (MFMA E/F, tile-sequential) =====================
// r13 structure + pair_score FUSED into mode-0's pre-barrier phase: each s2p
// entry is consumed by exactly one block (node-owner), so inlining duplicates
// nothing and kills a 6144-block kernel + one launch gap (~8-10us measured
// per-launch overhead across r6->r13). Lanes 0-11 of each node's 16-lane group
// split the 6 pair-dots (2 lanes x 100 elems, bf16 gathers that also pre-warm
// L2 for Phase D's re-gather of the same rows).
__global__ __launch_bounds__(NT, 4)
void round_kernel(
    const int*   __restrict__ atom_degree,
    const int*   __restrict__ bond_degree,
    const float* __restrict__ align_W,       // [2F] this round
    const float* __restrict__ align_b,       // [1]
    const unsigned short* __restrict__ WF,   // 7 fragment matrices this round
    const float* __restrict__ attend_b,
    const float* __restrict__ gru_bih,
    const float* __restrict__ gru_bhh,
    const float* __restrict__ nbr_b,         // mode0
    const unsigned short* __restrict__ PAb,  // mode0, bf16
    const unsigned short* __restrict__ PBb,  // mode0, bf16
    const float* __restrict__ s2_tab,        // mode1: per-node table
    const unsigned short* __restrict__ cur_inb, // [B,L,F] bf16 (s1, A, D, cv)
    float*       __restrict__ dst,           // mode1: fp32 output
    unsigned short* __restrict__ dstb,       // mode0: bf16 shadow out
    const float* __restrict__ alW2_next,     // mode0: round-1 alW2 for fused s2
    float*       __restrict__ s2_next,       // mode0: fused s2 output [NNODES]
    int mode)
{
    // XCD swizzle: all 8 tiles of a molecule share (blockIdx % 8) -> same XCD L2
    const int bid   = blockIdx.x;
    const int mol   = ((bid >> 6) << 3) | (bid & 7);
    const int tile  = (bid >> 3) & 7;
    const int node0 = mol * L_ + tile * NTILE;
    const int bL    = mol * L_;
    const int tid   = threadIdx.x;
    const int lane  = tid & 63;
    const int wave  = tid >> 6;

    __shared__ __align__(16) unsigned short curb  [NTILE][KPP];  // bf16 A-operands
    __shared__ __align__(16) unsigned short mixedb[NTILE][KPP];
    __shared__ __align__(16) unsigned short ctxb  [NTILE][KPP];
    __shared__ __align__(16) float nbrb_s[F_];
    __shared__ float sc_s [NQ];
    __shared__ float asum_s[NTILE];
    __shared__ float s2acc[NTILE];
    __shared__ int   nidx_s[NQ];
    __shared__ int   bidx_s[NQ];

    // zero K-pads [F_, KP) (MFMA reads them; pad x Wpad = 0 required)
    for (int idx = tid; idx < NTILE * (KP - F_); idx += NT) {
        const int n = idx / (KP - F_), k = F_ + idx % (KP - F_);
        curb[n][k] = 0; mixedb[n][k] = 0; ctxb[n][k] = 0;
    }
    if (tid < NTILE) s2acc[tid] = 0.0f;
    if (mode == 0 && tid < F_) nbrb_s[tid] = nbr_b[tid];

    // Phase A: own cur rows -> bf16 LDS (pure 16B copy from bf16 shadow)
    for (int idx = tid; idx < NTILE * KC8; idx += NT) {
        const int n = idx / KC8, kk = idx - n * KC8;
        *(uint4*)&curb[n][kk * 8] =
            *(const uint4*)(cur_inb + (size_t)(node0 + n) * F_ + kk * 8);
    }

    // Fused s1 + (mode0: inline pair-score) + align-score + softmax
    // (16 lanes per node, no intermediate barriers)
    {
        const int n = tid >> 4, sub = tid & 15;
        const unsigned short* crow = cur_inb + (size_t)(node0 + n) * F_;
        float s1 = 0.0f;
        for (int f = sub; f < F_; f += 16) s1 += b2f(crow[f]) * align_W[f];
        s1 += __shfl_xor(s1, 1, 16); s1 += __shfl_xor(s1, 2, 16);
        s1 += __shfl_xor(s1, 4, 16); s1 += __shfl_xor(s1, 8, 16);

        // mode0: inline pair scores. Lanes 0..11: pair j = sub>>1, half h = sub&1,
        // each covers 100 elems (chunks kk = h, h+2, ...).
        float s2v = 0.0f;
        if (mode == 0) {
            float ps = 0.0f;
            if (sub < 2 * D_) {
                const int j = sub >> 1, h = sub & 1;
                const int ni = atom_degree[(node0 + n) * D_ + j] & LMASK;
                const int bi = bond_degree[(node0 + n) * D_ + j] & LMASK;
                const unsigned short* pa = PAb + (size_t)(bL + ni) * F_;
                const unsigned short* pb = PBb + (size_t)(bL + bi) * F_;
                const float* w2 = align_W + F_;
                for (int kk = h; kk < KC8; kk += 2) {
                    const sh8 pa8 = *(const sh8*)(pa + kk * 8);
                    const sh8 pb8 = *(const sh8*)(pb + kk * 8);
                    #pragma unroll
                    for (int e = 0; e < 8; ++e) {
                        const int k = kk * 8 + e;
                        ps += lrelu(b2f((unsigned short)pa8[e])
                                  + b2f((unsigned short)pb8[e]) + nbr_b[k]) * w2[k];
                    }
                }
            }
            ps += __shfl_xor(ps, 1, 16);          // halves -> both lanes of the pair
            s2v = __shfl(ps, (sub << 1), 16);     // lane sub<6 grabs pair sub's score
        }

        // lanes 0..5 score their pair; 6..15 hold -inf filler
        float sc = -3.0e38f;
        int nidx = 0, bidx = 0;
        if (sub < D_) {
            nidx = atom_degree[(node0 + n) * D_ + sub] & LMASK;
            if (mode == 0) bidx = bond_degree[(node0 + n) * D_ + sub] & LMASK;
            const float s2 = (mode == 0) ? s2v : s2_tab[bL + nidx];
            sc = lrelu(s1 + s2 + align_b[0]);
            if (nidx == PAD_) sc += -9.0e8f;
        }
        // width-8 softmax (lanes 6,7: exp(-inf)=0 contribute nothing)
        float mx = sc;
        mx = fmaxf(mx, __shfl_xor(mx, 1, 8));
        mx = fmaxf(mx, __shfl_xor(mx, 2, 8));
        mx = fmaxf(mx, __shfl_xor(mx, 4, 8));
        const float ex = __expf(sc - mx);
        float ssum = ex;
        ssum += __shfl_xor(ssum, 1, 8);
        ssum += __shfl_xor(ssum, 2, 8);
        ssum += __shfl_xor(ssum, 4, 8);
        const float inv = 1.0f / ssum;
        const float aw = (sub < D_ && nidx != PAD_) ? ex * inv : 0.0f;
        if (sub < D_) {
            sc_s[n * D_ + sub]   = aw;
            nidx_s[n * D_ + sub] = nidx;
            if (mode == 0) bidx_s[n * D_ + sub] = bidx;
        }
        float as = aw;
        as += __shfl_xor(as, 1, 8);
        as += __shfl_xor(as, 2, 8);
        as += __shfl_xor(as, 4, 8);
        if (sub == 0) asum_s[n] = as;
    }
    __syncthreads();

    // Phase D: mixed[n] = sum_j attn_j * nbr_feat_j -> bf16 LDS (bf16 gathers)
    for (int idx = tid; idx < NTILE * KC8; idx += NT) {
        const int n = idx / KC8, kk = idx - n * KC8;
        const int c0 = kk * 8;
        float m[8];
        #pragma unroll
        for (int e = 0; e < 8; ++e) m[e] = 0.0f;
        if (mode == 0) {
            #pragma unroll
            for (int j = 0; j < D_; ++j) {
                const float a = sc_s[n * D_ + j];
                const sh8 pa8 = *(const sh8*)(PAb + (size_t)(bL + nidx_s[n*D_+j]) * F_ + c0);
                const sh8 pb8 = *(const sh8*)(PBb + (size_t)(bL + bidx_s[n*D_+j]) * F_ + c0);
                #pragma unroll
                for (int e = 0; e < 8; ++e)
                    m[e] += a * lrelu(b2f((unsigned short)pa8[e])
                                    + b2f((unsigned short)pb8[e]) + nbrb_s[c0 + e]);
            }
        } else {
            #pragma unroll
            for (int j = 0; j < D_; ++j) {
                const float a = sc_s[n * D_ + j];
                const sh8 v8 = *(const sh8*)(cur_inb + (size_t)(bL + nidx_s[n*D_+j]) * F_ + c0);
                #pragma unroll
                for (int e = 0; e < 8; ++e)
                    m[e] += a * b2f((unsigned short)v8[e]);
            }
        }
        uint4 w;
        w.x = (unsigned int)f2b(m[0]) | ((unsigned int)f2b(m[1]) << 16);
        w.y = (unsigned int)f2b(m[2]) | ((unsigned int)f2b(m[3]) << 16);
        w.z = (unsigned int)f2b(m[4]) | ((unsigned int)f2b(m[5]) << 16);
        w.w = (unsigned int)f2b(m[6]) | ((unsigned int)f2b(m[7]) << 16);
        *(uint4*)&mixedb[n][c0] = w;
    }
    __syncthreads();

    // ---- Phase E (MFMA, tile-sequential): ctx = elu(attend_W @ mixed + asum*b) ----
    for (int t = wave; t < NTL; t += 4) {
        f32x4 acc = {0.f, 0.f, 0.f, 0.f};
        #pragma unroll
        for (int ks = 0; ks < KSTEPS; ++ks)
            acc = __builtin_amdgcn_mfma_f32_16x16x32_bf16(
                AFRAG(mixedb, ks), bfrag(WF, 0, t, ks, lane), acc, 0, 0, 0);
        const int f = t * 16 + (lane & 15);
        if (f < F_) {
            const float bb = attend_b[f];
            #pragma unroll
            for (int rg = 0; rg < 4; ++rg) {
                const int node = ((lane >> 4) << 2) + rg;
                float c = acc[rg] + asum_s[node] * bb;
                c = (c > 0.0f) ? c : (__expf(c) - 1.0f);
                ctxb[node][f] = f2b(c);
            }
        }
    }
    __syncthreads();

    // ---- Phase F (MFMA, tile-sequential): GRU gates (+ fused next-round s2) ----
    float s2part[4] = {0.f, 0.f, 0.f, 0.f};
    for (int t = wave; t < NTL; t += 4) {
        f32x4 ar = {0.f,0.f,0.f,0.f}, az = {0.f,0.f,0.f,0.f};
        f32x4 ani = {0.f,0.f,0.f,0.f}, anh = {0.f,0.f,0.f,0.f};
        #pragma unroll
        for (int ks = 0; ks < KSTEPS; ++ks) {
            const sh8 ac = AFRAG(ctxb, ks);
            const sh8 ah = AFRAG(curb, ks);
            ar  = __builtin_amdgcn_mfma_f32_16x16x32_bf16(ac, bfrag(WF,1,t,ks,lane), ar, 0,0,0);
            ar  = __builtin_amdgcn_mfma_f32_16x16x32_bf16(ah, bfrag(WF,4,t,ks,lane), ar, 0,0,0);
            az  = __builtin_amdgcn_mfma_f32_16x16x32_bf16(ac, bfrag(WF,2,t,ks,lane), az, 0,0,0);
            az  = __builtin_amdgcn_mfma_f32_16x16x32_bf16(ah, bfrag(WF,5,t,ks,lane), az, 0,0,0);
            ani = __builtin_amdgcn_mfma_f32_16x16x32_bf16(ac, bfrag(WF,3,t,ks,lane), ani, 0,0,0);
            anh = __builtin_amdgcn_mfma_f32_16x16x32_bf16(ah, bfrag(WF,6,t,ks,lane), anh, 0,0,0);
        }
        const int f = t * 16 + (lane & 15);
        if (f < F_) {
            const float bir = gru_bih[f],        bhr = gru_bhh[f];
            const float biz = gru_bih[F_ + f],   bhz = gru_bhh[F_ + f];
            const float bin = gru_bih[2*F_ + f], bhn = gru_bhh[2*F_ + f];
            const float w2 = (mode == 0) ? alW2_next[f] : 0.0f;
            #pragma unroll
            for (int rg = 0; rg < 4; ++rg) {
                const int node = ((lane >> 4) << 2) + rg;
                const float r  = sigm(ar[rg] + bir + bhr);
                const float z  = sigm(az[rg] + biz + bhz);
                const float nn = fast_tanh(ani[rg] + bin + r * (anh[rg] + bhn));
                const size_t o = (size_t)(node0 + node) * F_ + f;
                const float cv = b2f(cur_inb[o]);
                const float h  = fmaxf((1.0f - z) * nn + z * cv, 0.0f);
                if (mode == 0) { dstb[o] = f2b(h); s2part[rg] += h * w2; }
                else           { dst[o] = h; }
            }
        }
    }

    if (mode == 0) {
        // reduce s2part across the 16 lanes of each quarter-wave, then LDS-accumulate
        #pragma unroll
        for (int rg = 0; rg < 4; ++rg) {
            float v = s2part[rg];
            v += __shfl_xor(v, 1, 16); v += __shfl_xor(v, 2, 16);
            v += __shfl_xor(v, 4, 16); v += __shfl_xor(v, 8, 16);
            if ((lane & 15) == 0) atomicAdd(&s2acc[((lane >> 4) << 2) + rg], v);
        }
        __syncthreads();
        if (tid < NTILE) s2_next[node0 + tid] = s2acc[tid];
    }
}

extern "C" __attribute__((visibility("default")))
void kernel_launch(void* const* d_in, const int* in_sizes, int n_in,
                   void* d_out, int out_size, void* d_ws, size_t ws_size,
                   hipStream_t stream) {
    const float* atom_list = (const float*)d_in[0];
    const float* bond_list = (const float*)d_in[1];
    const int*   atom_deg  = (const int*)d_in[2];
    const int*   bond_deg  = (const int*)d_in[3];
    const float* atom_W    = (const float*)d_in[4];
    const float* atom_b    = (const float*)d_in[5];
    const float* nbr_W     = (const float*)d_in[6];
    const float* nbr_b     = (const float*)d_in[7];
    const float* align_W   = (const float*)d_in[8];
    const float* align_b   = (const float*)d_in[9];
    const float* attend_W  = (const float*)d_in[10];
    const float* attend_b  = (const float*)d_in[11];
    const float* gru_Wih   = (const float*)d_in[12];
    const float* gru_Whh   = (const float*)d_in[13];
    const float* gru_bih   = (const float*)d_in[14];
    const float* gru_bhh   = (const float*)d_in[15];

    float* ws   = (float*)d_ws;
    float* s2b  = ws;                       // NNODES fp32 (round-1 per-node table)
    unsigned short* cur0b = (unsigned short*)(s2b + NNODES);          // NF bf16
    unsigned short* cur1b = cur0b + (size_t)NF;                        // NF bf16
    unsigned short* PAb   = cur1b + (size_t)NF;                        // NF bf16
    unsigned short* PBb   = PAb   + (size_t)NF;                        // NF bf16
    unsigned short* WF    = PBb   + (size_t)NF;                        // 1.3 MB frags
    float* out  = (float*)d_out;

    prep_frags_kernel<<<dim3(NPREP + NBF), dim3(NT), 0, stream>>>(
        atom_list, bond_list, atom_W, atom_b, nbr_W,
        attend_W, gru_Wih, gru_Whh,
        cur0b, PAb, PBb, WF);

    const dim3 grid(NNODES / NTILE);
    const size_t rframe = (size_t)7 * NTL * KSTEPS * 64 * 8;  // shorts per round

    round_kernel<<<grid, dim3(NT), 0, stream>>>(
        atom_deg, bond_deg, align_W, align_b,
        WF, attend_b, gru_bih, gru_bhh,
        nbr_b, PAb, PBb, /*s2_tab*/nullptr, cur0b, /*dst*/nullptr, /*dstb*/cur1b,
        /*alW2_next*/align_W + 2 * F_ + F_, /*s2_next*/s2b, 0);

    round_kernel<<<grid, dim3(NT), 0, stream>>>(
        atom_deg, bond_deg, align_W + 2 * F_, align_b + 1,
        WF + rframe, attend_b + F_, gru_bih + 3 * F_, gru_bhh + 3 * F_,
        nbr_b, PAb, PBb, s2b, cur1b, /*dst*/out, /*dstb*/nullptr,
        /*alW2_next*/nullptr, /*s2_next*/nullptr, 1);
}